// Round 2
// baseline (216.656 us; speedup 1.0000x reference)
//
#include <hip/hip_runtime.h>

#define HW_ 4096
#define OUTHW (128 * 128)

// ---------------- Kernel 1: 1x1 conv, Cin=512 -> Cout=256 ----------------
__global__ __launch_bounds__(256) void enc_conv_k(
    const float* __restrict__ x, const float* __restrict__ w,
    const float* __restrict__ bias, float* __restrict__ feat) {
  const int pix = blockIdx.x * 256 + threadIdx.x;   // 0..4095
  const int co0 = blockIdx.y * 16;                  // 16 co-groups
  const int b = blockIdx.z;
  const float* xb = x + (size_t)b * 512 * HW_ + pix;
  float acc[16];
#pragma unroll
  for (int j = 0; j < 16; ++j) acc[j] = bias[co0 + j];
  const float* wp = w + (size_t)co0 * 512;
  for (int ci = 0; ci < 512; ++ci) {
    const float xv = xb[(size_t)ci * HW_];
#pragma unroll
    for (int j = 0; j < 16; ++j)
      acc[j] = fmaf(xv, wp[j * 512 + ci], acc[j]);
  }
  float* fb = feat + (size_t)b * 256 * HW_ + pix;
#pragma unroll
  for (int j = 0; j < 16; ++j) fb[(size_t)(co0 + j) * HW_] = acc[j];
}

// ---------------- Kernel 2: 1x1 conv, 256 -> 64 ----------------
__global__ __launch_bounds__(256) void comp_conv_k(
    const float* __restrict__ feat, const float* __restrict__ w,
    const float* __restrict__ bias, float* __restrict__ comp) {
  const int pix = blockIdx.x * 256 + threadIdx.x;
  const int co0 = blockIdx.y * 16;                  // 4 co-groups
  const int b = blockIdx.z;
  const float* fb = feat + (size_t)b * 256 * HW_ + pix;
  float acc[16];
#pragma unroll
  for (int j = 0; j < 16; ++j) acc[j] = bias[co0 + j];
  const float* wp = w + (size_t)co0 * 256;
  for (int ci = 0; ci < 256; ++ci) {
    const float fv = fb[(size_t)ci * HW_];
#pragma unroll
    for (int j = 0; j < 16; ++j)
      acc[j] = fmaf(fv, wp[j * 256 + ci], acc[j]);
  }
  float* cb = comp + (size_t)b * 64 * HW_ + pix;
#pragma unroll
  for (int j = 0; j < 16; ++j) cb[(size_t)(co0 + j) * HW_] = acc[j];
}

// ---------------- Kernel 3: 3x3 conv pad 1, 64 -> 100 ----------------
__global__ __launch_bounds__(256) void ce_conv_k(
    const float* __restrict__ comp, const float* __restrict__ w,
    const float* __restrict__ bias, float* __restrict__ mask) {
  const int pix = blockIdx.x * 256 + threadIdx.x;
  const int y = pix >> 6, x0 = pix & 63;
  const int m0 = blockIdx.y * 10;                   // 10 m-groups
  const int b = blockIdx.z;
  const float* cb = comp + (size_t)b * 64 * HW_;
  float acc[10];
#pragma unroll
  for (int j = 0; j < 10; ++j) acc[j] = bias[m0 + j];
  for (int c = 0; c < 64; ++c) {
    const float* cc = cb + (size_t)c * HW_;
    const float* wc = w + ((size_t)m0 * 64 + c) * 9;
#pragma unroll
    for (int ky = 0; ky < 3; ++ky) {
      const int yy = y + ky - 1;
      const bool yok = (unsigned)yy < 64u;
#pragma unroll
      for (int kx = 0; kx < 3; ++kx) {
        const int xx = x0 + kx - 1;
        const float v =
            (yok && (unsigned)xx < 64u) ? cc[yy * 64 + xx] : 0.0f;
        const int tap = ky * 3 + kx;
#pragma unroll
        for (int j = 0; j < 10; ++j)
          acc[j] = fmaf(v, wc[(size_t)j * 576 + tap], acc[j]);
      }
    }
  }
  float* mb = mask + (size_t)b * 100 * HW_ + pix;
#pragma unroll
  for (int j = 0; j < 10; ++j) mb[(size_t)(m0 + j) * HW_] = acc[j];
}

// ------- Kernel 4: pixel-shuffle + softmax(25) + CARAFE reassembly -------
#define CH 32
__global__ __launch_bounds__(256) void carafe_k(
    const float* __restrict__ feat, const float* __restrict__ mask,
    float* __restrict__ out) {
  // grid: (8, 8, B*4); z = b*4 + cg (cg = 64-channel group)
  const int b = blockIdx.z >> 2;
  const int cg = blockIdx.z & 3;
  const int h0 = blockIdx.y * 8, w0 = blockIdx.x * 8;
  const int t = threadIdx.x;
  const int sp = t >> 2, pq = t & 3;     // src pixel in tile, sub-pixel
  const int hh = sp >> 3, ww = sp & 7;
  const int h = h0 + hh, w = w0 + ww;
  const int p = pq >> 1, q = pq & 1;

  // per-thread softmax over the 25 kernel taps for this (h,w,p,q)
  const float* mb = mask + (size_t)b * 100 * HW_ + h * 64 + w;
  float mv[25];
  float mmax = -3.4e38f;
#pragma unroll
  for (int k = 0; k < 25; ++k) {
    mv[k] = mb[(size_t)(k * 4 + pq) * HW_];
    mmax = fmaxf(mmax, mv[k]);
  }
  float ssum = 0.f;
#pragma unroll
  for (int k = 0; k < 25; ++k) {
    mv[k] = __expf(mv[k] - mmax);
    ssum += mv[k];
  }
  const float inv = 1.0f / ssum;
#pragma unroll
  for (int k = 0; k < 25; ++k) mv[k] *= inv;

  __shared__ float lds[CH * 144];  // CH channels x 12x12 halo tile
  const float* fb = feat + ((size_t)b * 256 + cg * 64) * HW_;
  float* ob = out + ((size_t)b * 256 + cg * 64) * OUTHW
            + (size_t)(2 * h + p) * 128 + (2 * w + q);
  for (int c0 = 0; c0 < 64; c0 += CH) {
    __syncthreads();
    for (int idx = t; idx < CH * 144; idx += 256) {
      const int c = idx / 144, r = idx - c * 144;
      const int ry = r / 12, rx = r - ry * 12;
      const int gy = h0 + ry - 2, gx = w0 + rx - 2;
      lds[idx] = ((unsigned)gy < 64u && (unsigned)gx < 64u)
                     ? fb[(size_t)(c0 + c) * HW_ + gy * 64 + gx]
                     : 0.0f;
    }
    __syncthreads();
    for (int c = 0; c < CH; ++c) {
      const float* lc = lds + c * 144 + hh * 12 + ww;
      float a = 0.f;
#pragma unroll
      for (int dy = 0; dy < 5; ++dy)
#pragma unroll
        for (int dx = 0; dx < 5; ++dx)
          a = fmaf(mv[dy * 5 + dx], lc[dy * 12 + dx], a);
      ob[(size_t)(c0 + c) * OUTHW] = a;
    }
  }
}

extern "C" void kernel_launch(void* const* d_in, const int* in_sizes, int n_in,
                              void* d_out, int out_size, void* d_ws, size_t ws_size,
                              hipStream_t stream) {
  const float* x = (const float*)d_in[0];
  const float* enc_w = (const float*)d_in[1];
  const float* enc_b = (const float*)d_in[2];
  const float* comp_w = (const float*)d_in[3];
  const float* comp_b = (const float*)d_in[4];
  const float* ce_w = (const float*)d_in[5];
  const float* ce_b = (const float*)d_in[6];
  float* out = (float*)d_out;

  float* feat = (float*)d_ws;                       // 2*256*4096 floats
  float* comp = feat + (size_t)2 * 256 * HW_;       // 2*64*4096 floats
  float* maskr = comp + (size_t)2 * 64 * HW_;       // 2*100*4096 floats

  enc_conv_k<<<dim3(16, 16, 2), 256, 0, stream>>>(x, enc_w, enc_b, feat);
  comp_conv_k<<<dim3(16, 4, 2), 256, 0, stream>>>(feat, comp_w, comp_b, comp);
  ce_conv_k<<<dim3(16, 10, 2), 256, 0, stream>>>(comp, ce_w, ce_b, maskr);
  carafe_k<<<dim3(8, 8, 8), 256, 0, stream>>>(feat, maskr, out);
}

// Round 3
// 122.229 us; speedup vs baseline: 1.7725x; 1.7725x over previous
//
#include <hip/hip_runtime.h>

#define HW_ 4096
#define OUTHW (128 * 128)

typedef __attribute__((ext_vector_type(8))) short bf16x8;
typedef __attribute__((ext_vector_type(4))) float f32x4;
typedef unsigned short ushort_t;
typedef unsigned int uint_t;

__device__ __forceinline__ ushort_t f2bf(float f) {
  uint_t u = __float_as_uint(f);
  uint_t r = (u + 0x7fffu + ((u >> 16) & 1u)) >> 16;
  return (ushort_t)r;
}

__device__ __forceinline__ void glds16(const void* g, void* l) {
  __builtin_amdgcn_global_load_lds(
      (const __attribute__((address_space(1))) unsigned int*)g,
      (__attribute__((address_space(3))) unsigned int*)l, 16, 0, 0);
}

#define KEY_(r) (((r) ^ ((r) >> 3)) & 7)

// ------------- Kernel 0: dtype conversion + ce_w re-layout -------------
// tasks: [0, 524288)        : x f32 -> xb bf16, 8 elems each
//        [524288, 540672)   : enc_w -> wb bf16, 8 elems each
//        [540672, 542720)   : comp_w -> cwb bf16, 8 elems each
//        [542720, 600320)   : ce_w[m][c][tap] -> cewr[c][m][tap] f32, 1 elem
__global__ __launch_bounds__(256) void convert_k(
    const float* __restrict__ x, const float* __restrict__ ew,
    const float* __restrict__ cw, const float* __restrict__ cew,
    ushort_t* __restrict__ xb, ushort_t* __restrict__ wb,
    ushort_t* __restrict__ cwb, float* __restrict__ cewr) {
  const long long i = (long long)blockIdx.x * 256 + threadIdx.x;
  if (i < 524288) {
    const float4 a = ((const float4*)x)[i * 2];
    const float4 b = ((const float4*)x)[i * 2 + 1];
    ushort_t o[8] = {f2bf(a.x), f2bf(a.y), f2bf(a.z), f2bf(a.w),
                     f2bf(b.x), f2bf(b.y), f2bf(b.z), f2bf(b.w)};
#pragma unroll
    for (int j = 0; j < 8; ++j) xb[i * 8 + j] = o[j];
  } else if (i < 540672) {
    const long long k = i - 524288;
    const float4 a = ((const float4*)ew)[k * 2];
    const float4 b = ((const float4*)ew)[k * 2 + 1];
    ushort_t o[8] = {f2bf(a.x), f2bf(a.y), f2bf(a.z), f2bf(a.w),
                     f2bf(b.x), f2bf(b.y), f2bf(b.z), f2bf(b.w)};
#pragma unroll
    for (int j = 0; j < 8; ++j) wb[k * 8 + j] = o[j];
  } else if (i < 542720) {
    const long long k = i - 540672;
    const float4 a = ((const float4*)cw)[k * 2];
    const float4 b = ((const float4*)cw)[k * 2 + 1];
    ushort_t o[8] = {f2bf(a.x), f2bf(a.y), f2bf(a.z), f2bf(a.w),
                     f2bf(b.x), f2bf(b.y), f2bf(b.z), f2bf(b.w)};
#pragma unroll
    for (int j = 0; j < 8; ++j) cwb[k * 8 + j] = o[j];
  } else if (i < 600320) {
    const int k = (int)(i - 542720);      // c*900 + m*9 + tap
    const int c = k / 900, r = k - c * 900;
    const int m = r / 9, tap = r - m * 9;
    cewr[k] = cew[(size_t)m * 576 + c * 9 + tap];
  }
}

// ------------- Kernel 1: enc 1x1 conv as bf16 MFMA GEMM -------------
// D[co][pix] = sum_ci wb[co][ci] * xb[b][ci][pix];  M=256,K=512,N=4096 per b
// tile 64co x 64pix, BK=64, 4 waves of 32x32
__global__ __launch_bounds__(256) void enc_mfma_k(
    const ushort_t* __restrict__ wb, const ushort_t* __restrict__ xb,
    const float* __restrict__ bias, float* __restrict__ feat) {
  const int b = blockIdx.z;
  const int co0 = blockIdx.y * 64;
  const int pix0 = blockIdx.x * 64;
  const int t = threadIdx.x;
  const int l = t & 63, w = t >> 6;
  const int wm = w >> 1, wn = w & 1;
  __shared__ ushort_t Atile[64 * 64];   // [co r][ci], slot-swizzled
  __shared__ ushort_t Btile[64 * 64];   // [pix r][ci], slot-swizzled
  const ushort_t* xbb = xb + (size_t)b * 512 * HW_;

  f32x4 acc[2][2];
#pragma unroll
  for (int m = 0; m < 2; ++m)
#pragma unroll
    for (int n = 0; n < 2; ++n) acc[m][n] = (f32x4){0.f, 0.f, 0.f, 0.f};

  for (int kt = 0; kt < 8; ++kt) {
    const int ci0 = kt * 64;
    __syncthreads();
    // ---- stage A via global_load_lds: 8 x 1KB wave-ops, wave w -> 2w,2w+1
#pragma unroll
    for (int oi = 0; oi < 2; ++oi) {
      const int o = 2 * w + oi;
      const int L = o * 1024 + l * 16;
      const int r = L >> 7, s = (L >> 4) & 7;
      const ushort_t* src =
          wb + (size_t)(co0 + r) * 512 + ci0 + ((s ^ KEY_(r)) * 8);
      glds16(src, (char*)Atile + o * 1024);
    }
    // ---- stage B (transpose + swizzle): 2 chunks of 8 pix x 1 ci
    bf16x8 bv[2];
#pragma unroll
    for (int i = 0; i < 2; ++i) {
      const int ch = t + 256 * i;
      const int c = ch >> 3, p8 = ch & 7;
      bv[i] = *(const bf16x8*)(xbb + (size_t)(ci0 + c) * HW_ + pix0 + p8 * 8);
    }
#pragma unroll
    for (int i = 0; i < 2; ++i) {
      const int ch = t + 256 * i;
      const int c = ch >> 3, p8 = ch & 7;
#pragma unroll
      for (int j = 0; j < 8; ++j) {
        const int r = p8 * 8 + j;
        *(ushort_t*)((char*)Btile + r * 128 + ((2 * c) ^ (KEY_(r) << 4))) =
            (ushort_t)bv[i][j];
      }
    }
    __syncthreads();
    // ---- fragments + MFMA
    const int g = l >> 4, lr = l & 15;
#pragma unroll
    for (int kk = 0; kk < 2; ++kk) {
      bf16x8 af[2], bf[2];
#pragma unroll
      for (int m = 0; m < 2; ++m) {
        const int r = wm * 32 + m * 16 + lr;
        const int slot = (kk * 4 + g) ^ KEY_(r);
        af[m] = *(const bf16x8*)((char*)Atile + r * 128 + slot * 16);
      }
#pragma unroll
      for (int n = 0; n < 2; ++n) {
        const int r = wn * 32 + n * 16 + lr;
        const int slot = (kk * 4 + g) ^ KEY_(r);
        bf[n] = *(const bf16x8*)((char*)Btile + r * 128 + slot * 16);
      }
#pragma unroll
      for (int m = 0; m < 2; ++m)
#pragma unroll
        for (int n = 0; n < 2; ++n)
          acc[m][n] = __builtin_amdgcn_mfma_f32_16x16x32_bf16(
              af[m], bf[n], acc[m][n], 0, 0, 0);
    }
  }
  // ---- epilogue
  float* fb = feat + (size_t)b * 256 * HW_;
#pragma unroll
  for (int m = 0; m < 2; ++m)
#pragma unroll
    for (int n = 0; n < 2; ++n)
#pragma unroll
      for (int j = 0; j < 4; ++j) {
        const int row = co0 + wm * 32 + m * 16 + (l >> 4) * 4 + j;
        const int col = pix0 + wn * 32 + n * 16 + (l & 15);
        fb[(size_t)row * HW_ + col] = acc[m][n][j] + bias[row];
      }
}

// ------------- Kernel 2: comp 1x1 conv as bf16 MFMA GEMM -------------
// D[co][pix] = sum_ci cwb[co][ci] * feat[b][ci][pix]; M=64,K=256,N=4096
// tile 64co x 32pix, BK=64, 4 waves of 32x16
__global__ __launch_bounds__(256) void comp_mfma_k(
    const ushort_t* __restrict__ cwb, const float* __restrict__ feat,
    const float* __restrict__ bias, float* __restrict__ comp) {
  const int b = blockIdx.z;
  const int pix0 = blockIdx.x * 32;
  const int t = threadIdx.x;
  const int l = t & 63, w = t >> 6;
  const int wm = w >> 1, wn = w & 1;
  __shared__ ushort_t Atile[64 * 64];   // [co][ci]
  __shared__ ushort_t Btile[32 * 64];   // [pix][ci]
  const float* fb = feat + (size_t)b * 256 * HW_;

  f32x4 acc[2];
#pragma unroll
  for (int m = 0; m < 2; ++m) acc[m] = (f32x4){0.f, 0.f, 0.f, 0.f};

  for (int kt = 0; kt < 4; ++kt) {
    const int ci0 = kt * 64;
    __syncthreads();
#pragma unroll
    for (int oi = 0; oi < 2; ++oi) {
      const int o = 2 * w + oi;
      const int L = o * 1024 + l * 16;
      const int r = L >> 7, s = (L >> 4) & 7;
      const ushort_t* src =
          cwb + (size_t)r * 256 + ci0 + ((s ^ KEY_(r)) * 8);
      glds16(src, (char*)Atile + o * 1024);
    }
    // B: thread t: ci = t>>2, p8 = t&3 (8 pix); fp32 load + cvt
    const int c = t >> 2, p8 = t & 3;
    const float4 v0 = *(const float4*)(fb + (size_t)(ci0 + c) * HW_ + pix0 + p8 * 8);
    const float4 v1 = *(const float4*)(fb + (size_t)(ci0 + c) * HW_ + pix0 + p8 * 8 + 4);
    const ushort_t e[8] = {f2bf(v0.x), f2bf(v0.y), f2bf(v0.z), f2bf(v0.w),
                           f2bf(v1.x), f2bf(v1.y), f2bf(v1.z), f2bf(v1.w)};
#pragma unroll
    for (int j = 0; j < 8; ++j) {
      const int r = p8 * 8 + j;
      *(ushort_t*)((char*)Btile + r * 128 + ((2 * c) ^ (KEY_(r) << 4))) = e[j];
    }
    __syncthreads();
    const int g = l >> 4, lr = l & 15;
#pragma unroll
    for (int kk = 0; kk < 2; ++kk) {
      bf16x8 af[2], bf0;
#pragma unroll
      for (int m = 0; m < 2; ++m) {
        const int r = wm * 32 + m * 16 + lr;
        const int slot = (kk * 4 + g) ^ KEY_(r);
        af[m] = *(const bf16x8*)((char*)Atile + r * 128 + slot * 16);
      }
      {
        const int r = wn * 16 + lr;
        const int slot = (kk * 4 + g) ^ KEY_(r);
        bf0 = *(const bf16x8*)((char*)Btile + r * 128 + slot * 16);
      }
#pragma unroll
      for (int m = 0; m < 2; ++m)
        acc[m] = __builtin_amdgcn_mfma_f32_16x16x32_bf16(af[m], bf0, acc[m],
                                                         0, 0, 0);
    }
  }
  float* cb = comp + (size_t)b * 64 * HW_;
#pragma unroll
  for (int m = 0; m < 2; ++m)
#pragma unroll
    for (int j = 0; j < 4; ++j) {
      const int row = wm * 32 + m * 16 + (l >> 4) * 4 + j;
      const int col = pix0 + wn * 16 + (l & 15);
      cb[(size_t)row * HW_ + col] = acc[m][j] + bias[row];
    }
}

// ------------- Kernel 3: ce 3x3 conv, 64 -> 100, Tm=5 -------------
__global__ __launch_bounds__(256) void ce_k(
    const float* __restrict__ comp, const float* __restrict__ wr,
    const float* __restrict__ bias, float* __restrict__ mask) {
  const int b = blockIdx.z, m0 = blockIdx.y * 5, py0 = blockIdx.x * 4;
  const int t = threadIdx.x;
  const int yy = t >> 6, xx = t & 63;
  __shared__ float ctile[16][6][66];
  const float* cb = comp + (size_t)b * 64 * HW_;
  float acc[5];
#pragma unroll
  for (int j = 0; j < 5; ++j) acc[j] = bias[m0 + j];

  for (int cc = 0; cc < 64; cc += 16) {
    __syncthreads();
    for (int idx = t; idx < 16 * 6 * 66; idx += 256) {
      const int c = idx / 396, r2 = idx - c * 396;
      const int ry = r2 / 66, rx = r2 - ry * 66;
      const int gy = py0 + ry - 1, gx = rx - 1;
      ((float*)ctile)[idx] =
          ((unsigned)gy < 64u && (unsigned)gx < 64u)
              ? cb[(size_t)(cc + c) * HW_ + gy * 64 + gx]
              : 0.f;
    }
    __syncthreads();
    for (int c = 0; c < 16; ++c) {
      const float* wc = wr + (size_t)(cc + c) * 900 + m0 * 9;
      float wv[45];
#pragma unroll
      for (int j = 0; j < 45; ++j) wv[j] = wc[j];
      float v[9];
#pragma unroll
      for (int dy = 0; dy < 3; ++dy)
#pragma unroll
        for (int dx = 0; dx < 3; ++dx) v[dy * 3 + dx] = ctile[c][yy + dy][xx + dx];
#pragma unroll
      for (int j = 0; j < 5; ++j)
#pragma unroll
        for (int tap = 0; tap < 9; ++tap)
          acc[j] = fmaf(wv[j * 9 + tap], v[tap], acc[j]);
    }
  }
  const int y = py0 + yy;
#pragma unroll
  for (int j = 0; j < 5; ++j)
    mask[(size_t)b * 100 * HW_ + (size_t)(m0 + j) * HW_ + y * 64 + xx] = acc[j];
}

// ------- Kernel 4: pixel-shuffle + softmax(25) + CARAFE reassembly -------
__global__ __launch_bounds__(256) void carafe_k(
    const float* __restrict__ feat, const float* __restrict__ mask,
    float* __restrict__ out) {
  const int b = blockIdx.z >> 2;
  const int cg = blockIdx.z & 3;
  const int h0 = blockIdx.y * 8, w0 = blockIdx.x * 8;
  const int t = threadIdx.x;
  const int sl = t >> 6;               // channel slice (wave)
  const int hh = (t >> 3) & 7, ww = t & 7;
  const int h = h0 + hh, w = w0 + ww;
  __shared__ float lds[64 * 144];
  const float* fb = feat + ((size_t)b * 256 + cg * 64) * HW_;
  for (int idx = t; idx < 64 * 144; idx += 256) {
    const int c = idx / 144, r = idx - c * 144;
    const int ry = r / 12, rx = r - ry * 12;
    const int gy = h0 + ry - 2, gx = w0 + rx - 2;
    lds[idx] = ((unsigned)gy < 64u && (unsigned)gx < 64u)
                   ? fb[(size_t)c * HW_ + gy * 64 + gx]
                   : 0.f;
  }
  // softmax for all 4 sub-pixels of this source pixel
  const float* mb = mask + (size_t)b * 100 * HW_ + h * 64 + w;
  float mv[4][25];
#pragma unroll
  for (int pq = 0; pq < 4; ++pq) {
    float mmax = -3.4e38f;
#pragma unroll
    for (int k = 0; k < 25; ++k) {
      mv[pq][k] = mb[(size_t)(k * 4 + pq) * HW_];
      mmax = fmaxf(mmax, mv[pq][k]);
    }
    float ssum = 0.f;
#pragma unroll
    for (int k = 0; k < 25; ++k) {
      mv[pq][k] = __expf(mv[pq][k] - mmax);
      ssum += mv[pq][k];
    }
    const float inv = 1.0f / ssum;
#pragma unroll
    for (int k = 0; k < 25; ++k) mv[pq][k] *= inv;
  }
  __syncthreads();
  float* ob = out + ((size_t)b * 256 + cg * 64) * OUTHW +
              (size_t)(2 * h) * 128 + 2 * w;
  for (int c = sl * 16; c < sl * 16 + 16; ++c) {
    const float* lc = lds + c * 144 + hh * 12 + ww;
    float a0 = 0.f, a1 = 0.f, a2 = 0.f, a3 = 0.f;
#pragma unroll
    for (int dy = 0; dy < 5; ++dy)
#pragma unroll
      for (int dx = 0; dx < 5; ++dx) {
        const float fv = lc[dy * 12 + dx];
        const int k = dy * 5 + dx;
        a0 = fmaf(mv[0][k], fv, a0);
        a1 = fmaf(mv[1][k], fv, a1);
        a2 = fmaf(mv[2][k], fv, a2);
        a3 = fmaf(mv[3][k], fv, a3);
      }
    float2 r0 = {a0, a1}, r1 = {a2, a3};
    *(float2*)(ob + (size_t)c * OUTHW) = r0;
    *(float2*)(ob + (size_t)c * OUTHW + 128) = r1;
  }
}

extern "C" void kernel_launch(void* const* d_in, const int* in_sizes, int n_in,
                              void* d_out, int out_size, void* d_ws, size_t ws_size,
                              hipStream_t stream) {
  const float* x = (const float*)d_in[0];
  const float* enc_w = (const float*)d_in[1];
  const float* enc_b = (const float*)d_in[2];
  const float* comp_w = (const float*)d_in[3];
  const float* comp_b = (const float*)d_in[4];
  const float* ce_w = (const float*)d_in[5];
  const float* ce_b = (const float*)d_in[6];
  float* out = (float*)d_out;

  char* ws = (char*)d_ws;
  ushort_t* xb   = (ushort_t*)(ws);                    // 8,388,608 B
  float*    comp = (float*)(ws);                       // reuse xb after enc
  float*    maskr= (float*)(ws + 2097152);             // 3,276,800 B
  float*    feat = (float*)(ws + 8388608);             // 8,388,608 B
  ushort_t* wb   = (ushort_t*)(ws + 16777216);         // 262,144 B
  ushort_t* cwb  = (ushort_t*)(ws + 17039360);         // 32,768 B
  float*    cewr = (float*)(ws + 17072128);            // 230,400 B

  convert_k<<<2345, 256, 0, stream>>>(x, enc_w, comp_w, ce_w, xb, wb, cwb, cewr);
  enc_mfma_k<<<dim3(64, 4, 2), 256, 0, stream>>>(wb, xb, enc_b, feat);
  comp_mfma_k<<<dim3(128, 1, 2), 256, 0, stream>>>(cwb, feat, comp_b, comp);
  ce_k<<<dim3(16, 20, 2), 256, 0, stream>>>(comp, cewr, ce_b, maskr);
  carafe_k<<<dim3(8, 8, 8), 256, 0, stream>>>(feat, maskr, out);
}

// Round 4
// 64.728 us; speedup vs baseline: 3.3472x; 1.8884x over previous
//
#include <hip/hip_runtime.h>

#define HW_ 4096
#define OUTHW (128 * 128)

typedef __attribute__((ext_vector_type(8))) short bf16x8;
typedef __attribute__((ext_vector_type(4))) float f32x4;
typedef __attribute__((ext_vector_type(4))) unsigned short ushort4_t;
typedef unsigned short ushort_t;
typedef unsigned int uint_t;

__device__ __forceinline__ ushort_t f2bf(float f) {
  uint_t u = __float_as_uint(f);
  uint_t r = (u + 0x7fffu + ((u >> 16) & 1u)) >> 16;
  return (ushort_t)r;
}

__device__ __forceinline__ void glds16(const void* g, void* l) {
  __builtin_amdgcn_global_load_lds(
      (const __attribute__((address_space(1))) unsigned int*)g,
      (__attribute__((address_space(3))) unsigned int*)l, 16, 0, 0);
}

#define KEY_(r) (((r) ^ ((r) >> 3)) & 7)

// ------------- Kernel 0: dtype conversion + ce_w re-layout -------------
// tasks: [0, 524288)        : x f32 -> xb bf16, 8 elems each
//        [524288, 540672)   : enc_w -> wb bf16, 8 elems each
//        [540672, 542720)   : comp_w -> cwb bf16, 8 elems each
//        [542720, 616448)   : ce_w[m][c][tap] -> cewb bf16 [128][tap*64+c], 1 elem
__global__ __launch_bounds__(256) void convert_k(
    const float* __restrict__ x, const float* __restrict__ ew,
    const float* __restrict__ cw, const float* __restrict__ cew,
    ushort_t* __restrict__ xb, ushort_t* __restrict__ wb,
    ushort_t* __restrict__ cwb, ushort_t* __restrict__ cewb) {
  const long long i = (long long)blockIdx.x * 256 + threadIdx.x;
  if (i < 524288) {
    const float4 a = ((const float4*)x)[i * 2];
    const float4 b = ((const float4*)x)[i * 2 + 1];
    ushort_t o[8] = {f2bf(a.x), f2bf(a.y), f2bf(a.z), f2bf(a.w),
                     f2bf(b.x), f2bf(b.y), f2bf(b.z), f2bf(b.w)};
#pragma unroll
    for (int j = 0; j < 8; ++j) xb[i * 8 + j] = o[j];
  } else if (i < 540672) {
    const long long k = i - 524288;
    const float4 a = ((const float4*)ew)[k * 2];
    const float4 b = ((const float4*)ew)[k * 2 + 1];
    ushort_t o[8] = {f2bf(a.x), f2bf(a.y), f2bf(a.z), f2bf(a.w),
                     f2bf(b.x), f2bf(b.y), f2bf(b.z), f2bf(b.w)};
#pragma unroll
    for (int j = 0; j < 8; ++j) wb[k * 8 + j] = o[j];
  } else if (i < 542720) {
    const long long k = i - 540672;
    const float4 a = ((const float4*)cw)[k * 2];
    const float4 b = ((const float4*)cw)[k * 2 + 1];
    ushort_t o[8] = {f2bf(a.x), f2bf(a.y), f2bf(a.z), f2bf(a.w),
                     f2bf(b.x), f2bf(b.y), f2bf(b.z), f2bf(b.w)};
#pragma unroll
    for (int j = 0; j < 8; ++j) cwb[k * 8 + j] = o[j];
  } else if (i < 616448) {
    const int k = (int)(i - 542720);      // dst: m*576 + tap*64 + c
    const int m = k / 576, r = k - m * 576;
    const int tap = r >> 6, c = r & 63;
    cewb[k] = (m < 100) ? f2bf(cew[(size_t)m * 576 + c * 9 + tap]) : (ushort_t)0;
  }
}

// ------------- Kernel 1: enc 1x1 conv as bf16 MFMA GEMM -------------
// D[co][pix] = sum_ci wb[co][ci] * xb[b][ci][pix];  M=256,K=512,N=4096 per b
__global__ __launch_bounds__(256) void enc_mfma_k(
    const ushort_t* __restrict__ wb, const ushort_t* __restrict__ xb,
    const float* __restrict__ bias, float* __restrict__ feat) {
  const int b = blockIdx.z;
  const int co0 = blockIdx.y * 64;
  const int pix0 = blockIdx.x * 64;
  const int t = threadIdx.x;
  const int l = t & 63, w = t >> 6;
  const int wm = w >> 1, wn = w & 1;
  __shared__ ushort_t Atile[64 * 64];   // [co r][ci], slot-swizzled
  __shared__ ushort_t Btile[64 * 64];   // [pix r][ci], slot-swizzled
  const ushort_t* xbb = xb + (size_t)b * 512 * HW_;

  f32x4 acc[2][2];
#pragma unroll
  for (int m = 0; m < 2; ++m)
#pragma unroll
    for (int n = 0; n < 2; ++n) acc[m][n] = (f32x4){0.f, 0.f, 0.f, 0.f};

  for (int kt = 0; kt < 8; ++kt) {
    const int ci0 = kt * 64;
    __syncthreads();
#pragma unroll
    for (int oi = 0; oi < 2; ++oi) {
      const int o = 2 * w + oi;
      const int L = o * 1024 + l * 16;
      const int r = L >> 7, s = (L >> 4) & 7;
      const ushort_t* src =
          wb + (size_t)(co0 + r) * 512 + ci0 + ((s ^ KEY_(r)) * 8);
      glds16(src, (char*)Atile + o * 1024);
    }
    bf16x8 bv[2];
#pragma unroll
    for (int i = 0; i < 2; ++i) {
      const int ch = t + 256 * i;
      const int c = ch >> 3, p8 = ch & 7;
      bv[i] = *(const bf16x8*)(xbb + (size_t)(ci0 + c) * HW_ + pix0 + p8 * 8);
    }
#pragma unroll
    for (int i = 0; i < 2; ++i) {
      const int ch = t + 256 * i;
      const int c = ch >> 3, p8 = ch & 7;
#pragma unroll
      for (int j = 0; j < 8; ++j) {
        const int r = p8 * 8 + j;
        *(ushort_t*)((char*)Btile + r * 128 + ((2 * c) ^ (KEY_(r) << 4))) =
            (ushort_t)bv[i][j];
      }
    }
    __syncthreads();
    const int g = l >> 4, lr = l & 15;
#pragma unroll
    for (int kk = 0; kk < 2; ++kk) {
      bf16x8 af[2], bf[2];
#pragma unroll
      for (int m = 0; m < 2; ++m) {
        const int r = wm * 32 + m * 16 + lr;
        const int slot = (kk * 4 + g) ^ KEY_(r);
        af[m] = *(const bf16x8*)((char*)Atile + r * 128 + slot * 16);
      }
#pragma unroll
      for (int n = 0; n < 2; ++n) {
        const int r = wn * 32 + n * 16 + lr;
        const int slot = (kk * 4 + g) ^ KEY_(r);
        bf[n] = *(const bf16x8*)((char*)Btile + r * 128 + slot * 16);
      }
#pragma unroll
      for (int m = 0; m < 2; ++m)
#pragma unroll
        for (int n = 0; n < 2; ++n)
          acc[m][n] = __builtin_amdgcn_mfma_f32_16x16x32_bf16(
              af[m], bf[n], acc[m][n], 0, 0, 0);
    }
  }
  float* fb = feat + (size_t)b * 256 * HW_;
#pragma unroll
  for (int m = 0; m < 2; ++m)
#pragma unroll
    for (int n = 0; n < 2; ++n)
#pragma unroll
      for (int j = 0; j < 4; ++j) {
        const int row = co0 + wm * 32 + m * 16 + (l >> 4) * 4 + j;
        const int col = pix0 + wn * 32 + n * 16 + (l & 15);
        fb[(size_t)row * HW_ + col] = acc[m][n][j] + bias[row];
      }
}

// ------------- Kernel 2: comp 1x1 conv as bf16 MFMA GEMM -------------
// out: compT[pix][64] bf16 (transposed, for ce im2col staging)
__global__ __launch_bounds__(256) void comp_mfma_k(
    const ushort_t* __restrict__ cwb, const float* __restrict__ feat,
    const float* __restrict__ bias, ushort_t* __restrict__ compT) {
  const int b = blockIdx.z;
  const int pix0 = blockIdx.x * 32;
  const int t = threadIdx.x;
  const int l = t & 63, w = t >> 6;
  const int wm = w >> 1, wn = w & 1;
  __shared__ ushort_t Atile[64 * 64];
  __shared__ ushort_t Btile[32 * 64];
  const float* fb = feat + (size_t)b * 256 * HW_;

  f32x4 acc[2];
#pragma unroll
  for (int m = 0; m < 2; ++m) acc[m] = (f32x4){0.f, 0.f, 0.f, 0.f};

  for (int kt = 0; kt < 4; ++kt) {
    const int ci0 = kt * 64;
    __syncthreads();
#pragma unroll
    for (int oi = 0; oi < 2; ++oi) {
      const int o = 2 * w + oi;
      const int L = o * 1024 + l * 16;
      const int r = L >> 7, s = (L >> 4) & 7;
      const ushort_t* src =
          cwb + (size_t)r * 256 + ci0 + ((s ^ KEY_(r)) * 8);
      glds16(src, (char*)Atile + o * 1024);
    }
    const int c = t >> 2, p8 = t & 3;
    const float4 v0 = *(const float4*)(fb + (size_t)(ci0 + c) * HW_ + pix0 + p8 * 8);
    const float4 v1 = *(const float4*)(fb + (size_t)(ci0 + c) * HW_ + pix0 + p8 * 8 + 4);
    const ushort_t e[8] = {f2bf(v0.x), f2bf(v0.y), f2bf(v0.z), f2bf(v0.w),
                           f2bf(v1.x), f2bf(v1.y), f2bf(v1.z), f2bf(v1.w)};
#pragma unroll
    for (int j = 0; j < 8; ++j) {
      const int r = p8 * 8 + j;
      *(ushort_t*)((char*)Btile + r * 128 + ((2 * c) ^ (KEY_(r) << 4))) = e[j];
    }
    __syncthreads();
    const int g = l >> 4, lr = l & 15;
#pragma unroll
    for (int kk = 0; kk < 2; ++kk) {
      bf16x8 af[2], bf0;
#pragma unroll
      for (int m = 0; m < 2; ++m) {
        const int r = wm * 32 + m * 16 + lr;
        const int slot = (kk * 4 + g) ^ KEY_(r);
        af[m] = *(const bf16x8*)((char*)Atile + r * 128 + slot * 16);
      }
      {
        const int r = wn * 16 + lr;
        const int slot = (kk * 4 + g) ^ KEY_(r);
        bf0 = *(const bf16x8*)((char*)Btile + r * 128 + slot * 16);
      }
#pragma unroll
      for (int m = 0; m < 2; ++m)
        acc[m] = __builtin_amdgcn_mfma_f32_16x16x32_bf16(af[m], bf0, acc[m],
                                                         0, 0, 0);
    }
  }
  // transposed bf16 epilogue: compT[pix][co]
  ushort_t* cb = compT + (size_t)b * HW_ * 64;
  const int pix = pix0 + wn * 16 + (l & 15);
#pragma unroll
  for (int m = 0; m < 2; ++m) {
    const int co_b = wm * 32 + m * 16 + (l >> 4) * 4;
    ushort4_t v;
#pragma unroll
    for (int j = 0; j < 4; ++j) v[j] = f2bf(acc[m][j] + bias[co_b + j]);
    *(ushort4_t*)(cb + (size_t)pix * 64 + co_b) = v;
  }
}

// ------------- Kernel 3: ce 3x3 conv as bf16 MFMA GEMM -------------
// mask[m][pix] = sum_{tap,c} cewb[m][tap*64+c] * compT[shift_tap(pix)][c]
// block: 32 pix (half row y) x 64 m-rows; 4 waves of 16m x 32pix
__global__ __launch_bounds__(256) void ce_mfma_k(
    const ushort_t* __restrict__ cewb, const ushort_t* __restrict__ compT,
    const float* __restrict__ bias, float* __restrict__ mask) {
  const int x0 = blockIdx.x * 32;
  const int y = blockIdx.y;
  const int b = blockIdx.z >> 1, mh = blockIdx.z & 1;
  const int t = threadIdx.x;
  const int l = t & 63, w = t >> 6;
  const int lr = l & 15, g = l >> 4;
  __shared__ ushort_t Bt[102 * 64];   // [halo pos (3x34)][c], slot-swizzled
  const ushort_t* cpb = compT + (size_t)b * HW_ * 64;

  // stage halo tile once (all 9 taps read from it)
  for (int ch = t; ch < 816; ch += 256) {
    const int pos = ch >> 3, s = ch & 7;
    const int ry = pos / 34, rx = pos - ry * 34;
    const int gy = y + ry - 1, gx = x0 + rx - 1;
    bf16x8 v = {0, 0, 0, 0, 0, 0, 0, 0};
    if ((unsigned)gy < 64u && (unsigned)gx < 64u)
      v = *(const bf16x8*)(cpb + (size_t)(gy * 64 + gx) * 64 + s * 8);
    *(bf16x8*)((char*)Bt + pos * 128 + ((s ^ KEY_(pos)) * 16)) = v;
  }
  __syncthreads();

  const int mrow = mh * 64 + w * 16 + lr;
  const ushort_t* arow = cewb + (size_t)mrow * 576;
  f32x4 acc[2];
#pragma unroll
  for (int n = 0; n < 2; ++n) acc[n] = (f32x4){0.f, 0.f, 0.f, 0.f};

#pragma unroll
  for (int tap = 0; tap < 9; ++tap) {
    const int ky = tap / 3, kx = tap - ky * 3;
#pragma unroll
    for (int ks = 0; ks < 2; ++ks) {
      const bf16x8 af = *(const bf16x8*)(arow + tap * 64 + ks * 32 + g * 8);
#pragma unroll
      for (int n = 0; n < 2; ++n) {
        const int r = ky * 34 + n * 16 + lr + kx;
        const int slot = (ks * 4 + g) ^ KEY_(r);
        const bf16x8 bfr = *(const bf16x8*)((char*)Bt + r * 128 + slot * 16);
        acc[n] = __builtin_amdgcn_mfma_f32_16x16x32_bf16(af, bfr, acc[n],
                                                         0, 0, 0);
      }
    }
  }
  const int pbase = y * 64 + x0;
#pragma unroll
  for (int n = 0; n < 2; ++n)
#pragma unroll
    for (int j = 0; j < 4; ++j) {
      const int m_r = mh * 64 + w * 16 + g * 4 + j;
      if (m_r < 100)
        mask[((size_t)b * 100 + m_r) * HW_ + pbase + n * 16 + lr] =
            acc[n][j] + bias[m_r];
    }
}

// ------- Kernel 4: pixel-shuffle + softmax(25) + CARAFE reassembly -------
__global__ __launch_bounds__(256) void carafe_k(
    const float* __restrict__ feat, const float* __restrict__ mask,
    float* __restrict__ out) {
  const int b = blockIdx.z >> 2;
  const int cg = blockIdx.z & 3;
  const int h0 = blockIdx.y * 8, w0 = blockIdx.x * 8;
  const int t = threadIdx.x;
  const int sl = t >> 6;               // channel slice (wave)
  const int hh = (t >> 3) & 7, ww = t & 7;
  const int h = h0 + hh, w = w0 + ww;
  __shared__ float lds[64 * 144];
  const float* fb = feat + ((size_t)b * 256 + cg * 64) * HW_;
  for (int idx = t; idx < 64 * 144; idx += 256) {
    const int c = idx / 144, r = idx - c * 144;
    const int ry = r / 12, rx = r - ry * 12;
    const int gy = h0 + ry - 2, gx = w0 + rx - 2;
    lds[idx] = ((unsigned)gy < 64u && (unsigned)gx < 64u)
                   ? fb[(size_t)c * HW_ + gy * 64 + gx]
                   : 0.f;
  }
  const float* mb = mask + (size_t)b * 100 * HW_ + h * 64 + w;
  float mv[4][25];
#pragma unroll
  for (int pq = 0; pq < 4; ++pq) {
    float mmax = -3.4e38f;
#pragma unroll
    for (int k = 0; k < 25; ++k) {
      mv[pq][k] = mb[(size_t)(k * 4 + pq) * HW_];
      mmax = fmaxf(mmax, mv[pq][k]);
    }
    float ssum = 0.f;
#pragma unroll
    for (int k = 0; k < 25; ++k) {
      mv[pq][k] = __expf(mv[pq][k] - mmax);
      ssum += mv[pq][k];
    }
    const float inv = 1.0f / ssum;
#pragma unroll
    for (int k = 0; k < 25; ++k) mv[pq][k] *= inv;
  }
  __syncthreads();
  float* ob = out + ((size_t)b * 256 + cg * 64) * OUTHW +
              (size_t)(2 * h) * 128 + 2 * w;
  for (int c = sl * 16; c < sl * 16 + 16; ++c) {
    const float* lc = lds + c * 144 + hh * 12 + ww;
    float a0 = 0.f, a1 = 0.f, a2 = 0.f, a3 = 0.f;
#pragma unroll
    for (int dy = 0; dy < 5; ++dy)
#pragma unroll
      for (int dx = 0; dx < 5; ++dx) {
        const float fv = lc[dy * 12 + dx];
        const int k = dy * 5 + dx;
        a0 = fmaf(mv[0][k], fv, a0);
        a1 = fmaf(mv[1][k], fv, a1);
        a2 = fmaf(mv[2][k], fv, a2);
        a3 = fmaf(mv[3][k], fv, a3);
      }
    float2 r0 = {a0, a1}, r1 = {a2, a3};
    *(float2*)(ob + (size_t)c * OUTHW) = r0;
    *(float2*)(ob + (size_t)c * OUTHW + 128) = r1;
  }
}

extern "C" void kernel_launch(void* const* d_in, const int* in_sizes, int n_in,
                              void* d_out, int out_size, void* d_ws, size_t ws_size,
                              hipStream_t stream) {
  const float* x = (const float*)d_in[0];
  const float* enc_w = (const float*)d_in[1];
  const float* enc_b = (const float*)d_in[2];
  const float* comp_w = (const float*)d_in[3];
  const float* comp_b = (const float*)d_in[4];
  const float* ce_w = (const float*)d_in[5];
  const float* ce_b = (const float*)d_in[6];
  float* out = (float*)d_out;

  char* ws = (char*)d_ws;
  ushort_t* xb    = (ushort_t*)(ws);                   // 8,388,608 B (convert->enc)
  ushort_t* compT = (ushort_t*)(ws);                   // 1,048,576 B (reuse after enc)
  float*    maskr = (float*)(ws + 1048576);            // 3,276,800 B (reuse after enc)
  float*    feat  = (float*)(ws + 8388608);            // 8,388,608 B
  ushort_t* wb    = (ushort_t*)(ws + 16777216);        // 262,144 B
  ushort_t* cwb   = (ushort_t*)(ws + 17039360);        // 32,768 B
  ushort_t* cewb  = (ushort_t*)(ws + 17072128);        // 147,456 B

  convert_k<<<2408, 256, 0, stream>>>(x, enc_w, comp_w, ce_w, xb, wb, cwb, cewb);
  enc_mfma_k<<<dim3(64, 4, 2), 256, 0, stream>>>(wb, xb, enc_b, feat);
  comp_mfma_k<<<dim3(128, 1, 2), 256, 0, stream>>>(cwb, feat, comp_b, compT);
  ce_mfma_k<<<dim3(2, 64, 4), 256, 0, stream>>>(cewb, compT, ce_b, maskr);
  carafe_k<<<dim3(8, 8, 8), 256, 0, stream>>>(feat, maskr, out);
}